// Round 3
// baseline (635.611 us; speedup 1.0000x reference)
//
#include <hip/hip_runtime.h>
#include <hip/hip_bf16.h>

#define NB 64
#define ND 1500
#define NT 1000
#define NA 512
#define KSTEPS 47   // ceil(1500/32)
#define STR 17      // Bs t-stride in dwords (16 k-pair dwords + 1 pad)
#define TT 128      // score t-tile
#define NTT 8       // ceil(NT/TT)

typedef __bf16 bf16x8 __attribute__((ext_vector_type(8)));
typedef float  f32x4  __attribute__((ext_vector_type(4)));

union BQ { unsigned u[4]; bf16x8 v; };

static __device__ __forceinline__ unsigned pack2(float lo, float hi) {
    __bf16 l = (__bf16)lo, h = (__bf16)hi;
    unsigned short lu = __builtin_bit_cast(unsigned short, l);
    unsigned short hu = __builtin_bit_cast(unsigned short, h);
    return ((unsigned)hu << 16) | (unsigned)lu;
}

// ---------------- kernel 0: pack w1 [D,NA] fp32 -> MFMA-fragment-ordered bf16 ----------------
// Layout: elem offset = ((ks*32 + a16)*64 + lane)*8, lane=(quad<<4)|col holds
// A[a = a16*16+col][k = ks*32 + quad*8 + j], j=0..7 (zero-padded for d >= ND).
__global__ void w1p_kernel(const float* __restrict__ w1, __bf16* __restrict__ w1p) {
    int g = blockIdx.x * 256 + threadIdx.x;       // one bf16x8 fragment-lane per thread
    if (g >= KSTEPS * 32 * 64) return;
    int lane = g & 63;
    int a16  = (g >> 6) & 31;
    int ks   = g >> 11;
    int col = lane & 15, quad = lane >> 4;
    int a  = a16 * 16 + col;
    int d0 = ks * 32 + quad * 8;
    bf16x8 o;
    #pragma unroll
    for (int j = 0; j < 8; ++j) {
        int d = d0 + j;
        o[j] = (d < ND) ? (__bf16)w1[d * NA + a] : (__bf16)0.0f;
    }
    *(bf16x8*)(w1p + (size_t)g * 8) = o;
}

// ---------------- kernel 1: scores[b,t] = sum_a relu(sum_d w1[d,a] X[b,d,t] + b1[a]) * w2[a] ----
// 512 threads = 8 waves; each wave owns 64 a-rows x all 128 t. TT=128 halves the
// per-CU w1p L2 sweep traffic (the round-2 bottleneck: 64KB/CU-step vs ~1800 B/cy/XCD L2).
// Raw s_barrier with lgkmcnt-only drain; X pipelined 2 steps deep; counted-vmcnt
// keeps X in flight through the MFMA phase (af issued before X -> MFMA waits vmcnt(2)).
__global__ __launch_bounds__(512, 2) void score_kernel(
    const float* __restrict__ X,         // [B, D, T] fp32
    const __bf16* __restrict__ w1p,      // fragment-packed, see w1p_kernel
    const float* __restrict__ b1,
    const float* __restrict__ w2,
    float* __restrict__ scores)          // [B, T] fp32
{
    __shared__ unsigned Bs[2][TT * STR];  // [t][k/2] pair-packed bf16, dbuf: 17408 B
    __shared__ float b1s[NA], w2s[NA];    // 4 KB
    __shared__ float wred[8][TT];         // 4 KB per-wave partial scores

    const int tt = blockIdx.x;
    const int b  = blockIdx.y;
    const int t0 = tt * TT;
    const int tid = threadIdx.x;

    for (int i = tid; i < NA; i += 512) { b1s[i] = b1[i]; w2s[i] = w2[i]; }

    const int lane = tid & 63;
    const int wave = tid >> 6;            // 0..7, wave owns a in [wave*64, wave*64+64)
    const int col = lane & 15;
    const int quad = lane >> 4;

    // X staging map: thread handles d-pair (2*dr2, 2*dr2+1), 4 consecutive t
    const int dr2  = tid >> 5;            // 0..15
    const int toff = (tid & 31) << 2;     // 0..124
    const float* xbase = X + (size_t)b * (ND * NT) + (t0 + toff);
    const bool tval = (t0 + toff) < NT;   // toff%4==0, NT%4==0 -> whole-float4 guard

    // per-lane base into packed w1: a16 = wave*4 + u
    const __bf16* wlane = w1p + (size_t)(wave * 4) * 512 + (size_t)lane * 8;

    f32x4 acc[4][8];
    #pragma unroll
    for (int u = 0; u < 4; ++u)
        #pragma unroll
        for (int i = 0; i < 8; ++i)
            acc[u][i] = (f32x4){0.f, 0.f, 0.f, 0.f};

    // ---- prologue: stage tile 0 into Bs[0]; preload tile 1 into regs ----
    {
        float4 g0 = {0,0,0,0}, g1 = {0,0,0,0};
        int d0 = 2 * dr2, d1 = d0 + 1;
        if (tval && d0 < ND) g0 = *(const float4*)(xbase + (size_t)d0 * NT);
        if (tval && d1 < ND) g1 = *(const float4*)(xbase + (size_t)d1 * NT);
        Bs[0][(toff + 0) * STR + dr2] = pack2(g0.x, g1.x);
        Bs[0][(toff + 1) * STR + dr2] = pack2(g0.y, g1.y);
        Bs[0][(toff + 2) * STR + dr2] = pack2(g0.z, g1.z);
        Bs[0][(toff + 3) * STR + dr2] = pack2(g0.w, g1.w);
    }
    float4 c0 = {0,0,0,0}, c1 = {0,0,0,0};   // X regs for tile ks+1 (written end of step ks)
    {
        int d0 = 32 + 2 * dr2, d1 = d0 + 1;
        if (tval && d0 < ND) c0 = *(const float4*)(xbase + (size_t)d0 * NT);
        if (tval && d1 < ND) c1 = *(const float4*)(xbase + (size_t)d1 * NT);
    }

    for (int ks = 0; ks < KSTEPS; ++ks) {
        const int cur = ks & 1;

        // A-frags for THIS step, issued first: MFMA's wait is vmcnt(2) -> the
        // two X loads below stay in flight across the barrier and MFMA phase.
        bf16x8 af[4];
        const __bf16* wk = wlane + (size_t)ks * (32 * 64 * 8);
        #pragma unroll
        for (int u = 0; u < 4; ++u)
            af[u] = *(const bf16x8*)(wk + (size_t)u * 512);

        // X loads for tile ks+2
        float4 n0 = {0,0,0,0}, n1 = {0,0,0,0};
        {
            int d0 = ks * 32 + 64 + 2 * dr2, d1 = d0 + 1;
            if (tval && d0 < ND) n0 = *(const float4*)(xbase + (size_t)d0 * NT);
            if (tval && d1 < ND) n1 = *(const float4*)(xbase + (size_t)d1 * NT);
        }

        // barrier with LDS-only drain: prev-step ds_writes visible, vmem stays in flight
        asm volatile("s_waitcnt lgkmcnt(0)" ::: "memory");
        __builtin_amdgcn_s_barrier();

        // B-frags: all 8 t-frags of this t-tile (each reused by 4 a-chunks)
        bf16x8 bq[8];
        #pragma unroll
        for (int i = 0; i < 8; ++i) {
            int tl = i * 16 + col;
            BQ q;
            #pragma unroll
            for (int jp = 0; jp < 4; ++jp)
                q.u[jp] = Bs[cur][tl * STR + quad * 4 + jp];
            bq[i] = q.v;
        }

        #pragma unroll
        for (int u = 0; u < 4; ++u)
            #pragma unroll
            for (int i = 0; i < 8; ++i)
                acc[u][i] = __builtin_amdgcn_mfma_f32_16x16x32_bf16(af[u], bq[i], acc[u][i], 0, 0, 0);

        // write tile ks+1 (regs loaded during step ks-1; latency fully covered)
        Bs[cur ^ 1][(toff + 0) * STR + dr2] = pack2(c0.x, c1.x);
        Bs[cur ^ 1][(toff + 1) * STR + dr2] = pack2(c0.y, c1.y);
        Bs[cur ^ 1][(toff + 2) * STR + dr2] = pack2(c0.z, c1.z);
        Bs[cur ^ 1][(toff + 3) * STR + dr2] = pack2(c0.w, c1.w);

        c0 = n0; c1 = n1;
    }

    // ---------------- epilogue: full a-sum of relu(h+b1)*w2 per t ----------------
    float part[8] = {0.f, 0.f, 0.f, 0.f, 0.f, 0.f, 0.f, 0.f};
    #pragma unroll
    for (int u = 0; u < 4; ++u)
        #pragma unroll
        for (int r = 0; r < 4; ++r) {
            int a = wave * 64 + u * 16 + quad * 4 + r;
            float bb = b1s[a], ww = w2s[a];
            #pragma unroll
            for (int i = 0; i < 8; ++i) {
                float h = acc[u][i][r] + bb;
                part[i] += fmaxf(h, 0.f) * ww;
            }
        }

    #pragma unroll
    for (int i = 0; i < 8; ++i) {
        float p = part[i];
        p += __shfl_down(p, 32);   // quad 2,3 -> 0,1
        p += __shfl_down(p, 16);   // quad 1 -> 0
        if (quad == 0) wred[wave][i * 16 + col] = p;
    }
    __syncthreads();
    if (tid < TT) {
        float s = 0.f;
        #pragma unroll
        for (int w = 0; w < 8; ++w) s += wred[w][tid];
        int t = t0 + tid;
        if (t < NT) scores[b * NT + t] = s;
    }
}

// ---------------- kernel 2: softmax over t, write A fp32 into d_out ----------------
__global__ __launch_bounds__(256) void softmax_kernel(
    const float* __restrict__ scores, float* __restrict__ A_out)
{
    __shared__ float red[256];
    const int b = blockIdx.x, tid = threadIdx.x;
    const float* s = scores + b * NT;
    float v[4], m = -1e30f;
    #pragma unroll
    for (int i = 0; i < 4; ++i) {
        int t = tid + i * 256;
        v[i] = (t < NT) ? s[t] : -1e30f;
        m = fmaxf(m, v[i]);
    }
    red[tid] = m; __syncthreads();
    for (int off = 128; off > 0; off >>= 1) {
        if (tid < off) red[tid] = fmaxf(red[tid], red[tid + off]);
        __syncthreads();
    }
    m = red[0]; __syncthreads();
    float sum = 0.f;
    #pragma unroll
    for (int i = 0; i < 4; ++i) {
        v[i] = __expf(v[i] - m);
        if (tid + i * 256 < NT) sum += v[i]; else v[i] = 0.f;
    }
    red[tid] = sum; __syncthreads();
    for (int off = 128; off > 0; off >>= 1) {
        if (tid < off) red[tid] += red[tid + off];
        __syncthreads();
    }
    float inv = 1.f / red[0];
    #pragma unroll
    for (int i = 0; i < 4; ++i) {
        int t = tid + i * 256;
        if (t < NT) A_out[b * NT + t] = v[i] * inv;
    }
}

// ---------------- kernel 3: E, std pooling — LDS-tiled, zero shuffles ----------------
// Block owns 64 d-rows; stages As once; loops 16 t-chunks of 64:
// coalesced global -> LDS [64][68] -> lanes-over-d compute with broadcast As reads.
#define DBLK 64
#define TC 64
#define NCH 16   // ceil(NT/TC)
__global__ __launch_bounds__(256) void pool_kernel(
    const float* __restrict__ X, const float* __restrict__ A,   // A = d_out[0:NB*NT]
    float* __restrict__ outE)                                   // d_out + NB*NT
{
    __shared__ float As[1024];        // zero-padded past NT
    __shared__ float Xs[DBLK][68];    // pad 68: float4-aligned rows, spread banks
    const int b = blockIdx.x;
    const int d0 = blockIdx.y * DBLK;
    const int tid = threadIdx.x;

    for (int t = tid; t < 1024; t += 256) As[t] = (t < NT) ? A[b * NT + t] : 0.f;

    const int lrow = tid >> 2, lseg = tid & 3;   // staging: row, 16-float segment
    const int r = tid & 63, w = tid >> 6;        // compute: lane=row, wave=t-quarter
    const float* xrow = X + (size_t)b * (ND * NT) + (size_t)(d0 + lrow) * NT;
    const bool rowv = (d0 + lrow) < ND;

    float e = 0.f, q = 0.f;
    for (int ch = 0; ch < NCH; ++ch) {
        const int tc = ch * TC;
        // issue global loads before the barrier -> latency hides under the wait
        float4 v[4];
        #pragma unroll
        for (int j = 0; j < 4; ++j) {
            int t = tc + j * 16 + lseg * 4;
            v[j] = (rowv && t < NT) ? *(const float4*)(xrow + t) : (float4){0.f, 0.f, 0.f, 0.f};
        }
        __syncthreads();               // prev chunk's compute done (and As ready at ch=0)
        #pragma unroll
        for (int j = 0; j < 4; ++j)
            *(float4*)(&Xs[lrow][j * 16 + lseg * 4]) = v[j];
        __syncthreads();               // tile visible
        #pragma unroll
        for (int j = 0; j < 4; ++j) {
            float4 x4 = *(const float4*)(&Xs[r][w * 16 + j * 4]);
            float4 a4 = *(const float4*)(&As[tc + w * 16 + j * 4]);  // wave-uniform -> broadcast
            float xa;
            xa = x4.x * a4.x; e += xa; q += x4.x * xa;
            xa = x4.y * a4.y; e += xa; q += x4.y * xa;
            xa = x4.z * a4.z; e += xa; q += x4.z * xa;
            xa = x4.w * a4.w; e += xa; q += x4.w * xa;
        }
    }

    __syncthreads();
    float* red = &Xs[0][0];            // reuse tile space for the 4-way reduction
    red[w * 64 + r] = e;
    red[256 + w * 64 + r] = q;
    __syncthreads();
    if (tid < DBLK) {
        float ee = red[tid] + red[64 + tid] + red[128 + tid] + red[192 + tid];
        float qq = red[256 + tid] + red[320 + tid] + red[384 + tid] + red[448 + tid];
        int d = d0 + tid;
        if (d < ND) {
            outE[b * 3000 + d] = ee;
            outE[b * 3000 + 1500 + d] = sqrtf(fmaxf(qq - ee * ee, 0.f) + 1e-5f);
        }
    }
}

extern "C" void kernel_launch(void* const* d_in, const int* in_sizes, int n_in,
                              void* d_out, int out_size, void* d_ws, size_t ws_size,
                              hipStream_t stream) {
    const float* X  = (const float*)d_in[0];
    const float* w1 = (const float*)d_in[1];
    const float* b1 = (const float*)d_in[2];
    const float* w2 = (const float*)d_in[3];
    // d_in[4] = bias_2: scalar added to every t -> cancels in softmax over t; outputs unaffected.

    char* ws = (char*)d_ws;
    __bf16* w1p    = (__bf16*)ws;                                     // 47*32*64*8*2 = 1,540,096 B
    float*  scores = (float*)(ws + (size_t)KSTEPS * 32 * 64 * 8 * 2); // NB*NT*4 = 256,000 B

    float* out = (float*)d_out;                          // [A : NB*NT][layer_out : NB*3000]

    w1p_kernel<<<(KSTEPS * 32 * 64 + 255) / 256, 256, 0, stream>>>(w1, w1p);
    score_kernel<<<dim3(NTT, NB), 512, 0, stream>>>(X, w1p, b1, w2, scores);
    softmax_kernel<<<NB, 256, 0, stream>>>(scores, out);
    pool_kernel<<<dim3(NB, (ND + DBLK - 1) / DBLK), 256, 0, stream>>>(X, out, out + NB * NT);
}